// Round 3
// baseline (2947.272 us; speedup 1.0000x reference)
//
#include <hip/hip_runtime.h>
#include <hip/hip_bf16.h>

// feat (in d_ws): [nbc][127][256][256] fp32 — channels x1..x4 only.
// Channel c of the reference's 128-ch feat maps to: c==0 -> x (d_in[0]),
// c>=1 -> feat[c-1]. All dense-block concats are contiguous prefixes.
// Small buffers (pooled/hbuf/wgen, global-batch-indexed) live at d_ws tail.

#define HW 65536
#define IMG 256

// Direct 3x3 conv, pad 1. Reads x (ic=0) + feat channels [1,Cin),
// writes feat channels [Cin-1, Cin-1+COUT) with leaky-relu.
// One block = one image row (256 threads = 256 columns).
template <int COUT>
__global__ __launch_bounds__(256) void conv3x3_k(const float* __restrict__ x,
                                                 float* __restrict__ feat,
                                                 const float* __restrict__ w,
                                                 const float* __restrict__ bias,
                                                 int Cin, int b0) {
    const int wx = threadIdx.x;
    const int h  = blockIdx.x & 255;
    const int bl = blockIdx.x >> 8;          // local sample in chunk

    float acc[COUT];
#pragma unroll
    for (int oc = 0; oc < COUT; ++oc) acc[oc] = bias[oc];

    const float* xb = x + (size_t)(b0 + bl) * HW;
    const float* fb = feat + (size_t)bl * 127 * HW;
    const bool hm = (h > 0), hp = (h < 255);
    const bool wm = (wx > 0), wp = (wx < 255);

    for (int ic = 0; ic < Cin; ++ic) {
        const float* src = (ic == 0) ? xb : (fb + (size_t)(ic - 1) * HW);
        const float* p  = src + h * IMG;
        const float* pm = p - IMG;
        const float* pp = p + IMG;
        float v[9];
        v[0] = (hm && wm) ? pm[wx - 1] : 0.f;
        v[1] = hm ? pm[wx] : 0.f;
        v[2] = (hm && wp) ? pm[wx + 1] : 0.f;
        v[3] = wm ? p[wx - 1] : 0.f;
        v[4] = p[wx];
        v[5] = wp ? p[wx + 1] : 0.f;
        v[6] = (hp && wm) ? pp[wx - 1] : 0.f;
        v[7] = hp ? pp[wx] : 0.f;
        v[8] = (hp && wp) ? pp[wx + 1] : 0.f;

        const float* wic = w + ic * 9;
#pragma unroll
        for (int oc = 0; oc < COUT; ++oc) {
            const float* wo = wic + oc * Cin * 9;   // wave-uniform -> s_load
            float s = acc[oc];
#pragma unroll
            for (int k = 0; k < 9; ++k) s = fmaf(v[k], wo[k], s);
            acc[oc] = s;
        }
    }

    float* ob = feat + (size_t)bl * 127 * HW + (size_t)(Cin - 1) * HW
              + h * IMG + wx;
#pragma unroll
    for (int oc = 0; oc < COUT; ++oc) {
        float s = acc[oc];
        s = (s >= 0.f) ? s : 0.2f * s;
        ob[(size_t)oc * HW] = s;
    }
}

// Global average pool: one block per (local sample, channel).
__global__ __launch_bounds__(256) void pool_k(const float* __restrict__ x,
                                              const float* __restrict__ feat,
                                              float* __restrict__ pooled,
                                              int b0) {
    int bc = blockIdx.x;            // bl*128 + c
    int c  = bc & 127;
    int bl = bc >> 7;
    const float* p = (c == 0) ? (x + (size_t)(b0 + bl) * HW)
                              : (feat + ((size_t)bl * 127 + (c - 1)) * HW);
    float s = 0.f;
    for (int i = threadIdx.x; i < HW; i += 256) s += p[i];
#pragma unroll
    for (int off = 32; off >= 1; off >>= 1) s += __shfl_down(s, off);
    __shared__ float wsum[4];
    int lane = threadIdx.x & 63, wid = threadIdx.x >> 6;
    if (lane == 0) wsum[wid] = s;
    __syncthreads();
    if (threadIdx.x == 0)
        pooled[(b0 + bl) * 128 + c] =
            (wsum[0] + wsum[1] + wsum[2] + wsum[3]) * (1.f / 65536.f);
}

// h = relu((pooled @ w1.T) * gamma + beta)
__global__ __launch_bounds__(256) void mlp1_k(const float* __restrict__ pooled,
                                              const float* __restrict__ w1,
                                              const float* __restrict__ g,
                                              const float* __restrict__ bb,
                                              float* __restrict__ hbuf,
                                              int b0, int nbc) {
    int t = threadIdx.x;
    if (t >= nbc * 32) return;
    int gb = b0 + (t >> 5), r = t & 31;
    float s = 0.f;
    for (int c = 0; c < 128; ++c) s += pooled[gb * 128 + c] * w1[r * 128 + c];
    s = s * g[r] + bb[r];
    hbuf[gb * 32 + r] = (s > 0.f) ? s : 0.f;
}

// wgen = h @ w2.T + b2
__global__ __launch_bounds__(256) void mlp2_k(const float* __restrict__ hbuf,
                                              const float* __restrict__ w2,
                                              const float* __restrict__ b2,
                                              float* __restrict__ wgen,
                                              int b0, int nbc) {
    int idx = blockIdx.x * 256 + threadIdx.x;
    if (idx >= nbc * 6272) return;
    int bl = idx / 6272, i = idx - bl * 6272;
    int gb = b0 + bl;
    float s = b2[i];
    for (int r = 0; r < 32; ++r) s += hbuf[gb * 32 + r] * w2[i * 32 + r];
    wgen[gb * 6272 + i] = s;
}

// Fused: per-sample 7x7 depthwise conv (+bias,+lrelu) -> 3x3 conv to 3 ch.
// One block = 16x16 output tile. Per channel: 24x24 feat tile in LDS ->
// 18x18 x45 tile in LDS (zeroed outside image!) -> conv5 into 3 regs.
__global__ __launch_bounds__(256) void dwc5_k(const float* __restrict__ x,
                                              const float* __restrict__ feat,
                                              const float* __restrict__ wgen,
                                              const float* __restrict__ dwb,
                                              const float* __restrict__ c5w,
                                              const float* __restrict__ c5b,
                                              float* __restrict__ out,
                                              int b0) {
    __shared__ float ftile[24][24];
    __shared__ float xtile[18][19];

    int bi = blockIdx.x;
    int bl = bi >> 8;
    int gb = b0 + bl;
    int rem = bi & 255;
    int th0 = (rem >> 4) << 4;
    int tw0 = (rem & 15) << 4;
    int tid = threadIdx.x;
    int ty = tid >> 4, tx = tid & 15;

    float acc0 = 0.f, acc1 = 0.f, acc2 = 0.f;
    const float* xb = x + (size_t)gb * HW;
    const float* fb = feat + (size_t)bl * 127 * HW;
    const float* wg = wgen + gb * 6272;

    for (int c = 0; c < 128; ++c) {
        const float* fc = (c == 0) ? xb : (fb + (size_t)(c - 1) * HW);
        // stage 24x24 feat tile (zero-padded at image borders)
        for (int i = tid; i < 576; i += 256) {
            int yy = i / 24, xx = i - yy * 24;
            int gh = th0 - 4 + yy, gw = tw0 - 4 + xx;
            float v = 0.f;
            if (gh >= 0 && gh < 256 && gw >= 0 && gw < 256) v = fc[gh * 256 + gw];
            ftile[yy][xx] = v;
        }
        __syncthreads();

        // 18x18 x45 tile: 7x7 dw conv + bias + lrelu; ZERO outside image
        const float* wk = wg + c * 49;   // uniform
        float bias_c = dwb[c];
        for (int j = tid; j < 324; j += 256) {
            int yy = j / 18, xx = j - yy * 18;
            int gy = th0 - 1 + yy, gx = tw0 - 1 + xx;
            float v = 0.f;
            if (gy >= 0 && gy < 256 && gx >= 0 && gx < 256) {
                float s = 0.f;
#pragma unroll
                for (int ky = 0; ky < 7; ++ky)
#pragma unroll
                    for (int kx = 0; kx < 7; ++kx)
                        s = fmaf(ftile[yy + ky][xx + kx], wk[ky * 7 + kx], s);
                s += bias_c;
                v = (s >= 0.f) ? s : 0.2f * s;
            }
            xtile[yy][xx] = v;
        }
        __syncthreads();

        // conv5 accumulate (3 out channels)
        const float* w5 = c5w + c * 9;   // uniform; oc stride = 128*9 = 1152
#pragma unroll
        for (int ky = 0; ky < 3; ++ky)
#pragma unroll
            for (int kx = 0; kx < 3; ++kx) {
                float xv = xtile[ty + ky][tx + kx];
                acc0 = fmaf(xv, w5[0 * 1152 + ky * 3 + kx], acc0);
                acc1 = fmaf(xv, w5[1 * 1152 + ky * 3 + kx], acc1);
                acc2 = fmaf(xv, w5[2 * 1152 + ky * 3 + kx], acc2);
            }
        __syncthreads();
    }

    size_t ob = ((size_t)gb * 3) * HW + (size_t)(th0 + ty) * 256 + (tw0 + tx);
    out[ob]          = acc0 + c5b[0];
    out[ob + HW]     = acc1 + c5b[1];
    out[ob + 2 * HW] = acc2 + c5b[2];
}

extern "C" void kernel_launch(void* const* d_in, const int* in_sizes, int n_in,
                              void* d_out, int out_size, void* d_ws, size_t ws_size,
                              hipStream_t stream) {
    (void)in_sizes; (void)n_in; (void)out_size;
    const float* x     = (const float*)d_in[0];
    const float* c1w   = (const float*)d_in[1];
    const float* c1b   = (const float*)d_in[2];
    const float* c2w   = (const float*)d_in[3];
    const float* c2b   = (const float*)d_in[4];
    const float* c3w   = (const float*)d_in[5];
    const float* c3b   = (const float*)d_in[6];
    const float* c4w   = (const float*)d_in[7];
    const float* c4b   = (const float*)d_in[8];
    const float* dw_w1 = (const float*)d_in[9];
    const float* bn_g  = (const float*)d_in[10];
    const float* bn_b  = (const float*)d_in[11];
    const float* dw_w2 = (const float*)d_in[12];
    const float* dw_b2 = (const float*)d_in[13];
    const float* dwb   = (const float*)d_in[14];
    const float* c5w   = (const float*)d_in[15];
    const float* c5b   = (const float*)d_in[16];
    float* out = (float*)d_out;

    // Small buffers at d_ws tail (256 KB reserved): pooled[1024], hbuf[256],
    // wgen[50176] — indexed by GLOBAL batch, shared across chunks.
    const size_t small_bytes = 262144;
    size_t tail_off = (ws_size > small_bytes)
                          ? ((ws_size - small_bytes) & ~(size_t)255) : 0;
    float* smallp = (float*)((char*)d_ws + tail_off);
    float* pooled = smallp;
    float* hbuf   = smallp + 1024;
    float* wgen   = smallp + 1280;
    float* feat   = (float*)d_ws;

    // Largest chunk (samples per pass) whose feat fits below the tail.
    int nbc = 8;
    while (nbc > 1 && (size_t)nbc * 127 * HW * 4 > tail_off) nbc >>= 1;

    for (int b0 = 0; b0 < 8; b0 += nbc) {
        conv3x3_k<32><<<nbc * 256, 256, 0, stream>>>(x, feat, c1w, c1b, 1,  b0);
        conv3x3_k<32><<<nbc * 256, 256, 0, stream>>>(x, feat, c2w, c2b, 33, b0);
        conv3x3_k<32><<<nbc * 256, 256, 0, stream>>>(x, feat, c3w, c3b, 65, b0);
        conv3x3_k<31><<<nbc * 256, 256, 0, stream>>>(x, feat, c4w, c4b, 97, b0);
        pool_k<<<nbc * 128, 256, 0, stream>>>(x, feat, pooled, b0);
        mlp1_k<<<1, 256, 0, stream>>>(pooled, dw_w1, bn_g, bn_b, hbuf, b0, nbc);
        mlp2_k<<<(nbc * 6272 + 255) / 256, 256, 0, stream>>>(hbuf, dw_w2, dw_b2,
                                                             wgen, b0, nbc);
        dwc5_k<<<nbc * 256, 256, 0, stream>>>(x, feat, wgen, dwb, c5w, c5b,
                                              out, b0);
    }
}

// Round 4
// 884.225 us; speedup vs baseline: 3.3332x; 3.3332x over previous
//
#include <hip/hip_runtime.h>
#include <hip/hip_bf16.h>

// feat (d_ws): NHWC f16 [8][256][256][128]. Physical channel order:
//   phys 0..31 = x1, 32..63 = x2, 64..95 = x3, 96..126 = x4, 127 = x.
// Logical (reference) ic: 0 -> phys127, ic>=1 -> phys ic-1.
// All conv output bases (0,32,64,96) are 16B-aligned; K-chunks of 32 phys ch.

typedef _Float16 f16;
typedef _Float16 f16x2 __attribute__((ext_vector_type(2)));
typedef _Float16 f16x8 __attribute__((ext_vector_type(8)));
typedef float f32x16 __attribute__((ext_vector_type(16)));

#define IMG 256
#define HW 65536
#define CH 128

static __device__ __forceinline__ size_t fidx(int b, int h, int w) {
    return (((size_t)b * IMG + h) * IMG + w) * CH;
}

// Build Wt[tap][oc32][phys128] f16 from w[oc][ic][3][3] f32 (zero-padded).
__global__ __launch_bounds__(256) void prep_wt_k(const float* __restrict__ src,
                                                 f16* __restrict__ dst,
                                                 int Cin, int COUT) {
    int idx = blockIdx.x * 256 + threadIdx.x;
    if (idx >= 9 * 32 * 128) return;
    int tap = idx >> 12;
    int oc  = (idx >> 7) & 31;
    int pc  = idx & 127;
    int ic  = (pc == 127) ? 0 : pc + 1;
    float v = 0.f;
    if (oc < COUT && ic < Cin) v = src[(oc * Cin + ic) * 9 + tap];
    dst[idx] = (f16)v;
}

// conv1 (Cin=1) direct fp32; writes x1 -> phys 0..31 and x -> phys 127.
__global__ __launch_bounds__(256) void conv1_k(const float* __restrict__ x,
                                               f16* __restrict__ feat,
                                               const float* __restrict__ w,
                                               const float* __restrict__ bias) {
    int wx = threadIdx.x, h = blockIdx.x & 255, b = blockIdx.x >> 8;
    const float* p = x + (size_t)b * HW + h * IMG;
    bool hm = h > 0, hp = h < 255, wm = wx > 0, wp = wx < 255;
    float v[9];
    v[0] = (hm && wm) ? p[wx - 1 - IMG] : 0.f;
    v[1] = hm ? p[wx - IMG] : 0.f;
    v[2] = (hm && wp) ? p[wx + 1 - IMG] : 0.f;
    v[3] = wm ? p[wx - 1] : 0.f;
    v[4] = p[wx];
    v[5] = wp ? p[wx + 1] : 0.f;
    v[6] = (hp && wm) ? p[wx - 1 + IMG] : 0.f;
    v[7] = hp ? p[wx + IMG] : 0.f;
    v[8] = (hp && wp) ? p[wx + 1 + IMG] : 0.f;

    float acc[32];
#pragma unroll
    for (int oc = 0; oc < 32; ++oc) {
        float s = bias[oc];
#pragma unroll
        for (int k = 0; k < 9; ++k) s = fmaf(v[k], w[oc * 9 + k], s);
        acc[oc] = (s >= 0.f) ? s : 0.2f * s;
    }
    f16* op = feat + fidx(b, h, wx);
#pragma unroll
    for (int oc = 0; oc < 32; oc += 2) {
        f16x2 pr = {(f16)acc[oc], (f16)acc[oc + 1]};
        *(f16x2*)(op + oc) = pr;
    }
    op[127] = (f16)v[4];
}

// Implicit-GEMM 3x3 conv via mfma_f32_32x32x16_f16.
// Block = 32 oc x 128 px (one image row half); 4 waves x 32 px each.
// K-loop over 32-ch chunks (cmask selects chunks with nonzero weights),
// 9 shifted tap-GEMMs per chunk. LDS tile [3 rows][130 px][32 ch] f16
// with XOR swizzle on the 16B-unit index for conflict-free b128 r/w.
__global__ __launch_bounds__(256) void convm_k(f16* __restrict__ feat,
                                               const f16* __restrict__ Wt,
                                               const float* __restrict__ bias,
                                               int outbase, int cmask, int COUT) {
    __shared__ f16 St[3 * 130 * 32];
    int tid = threadIdx.x;
    int wave = tid >> 6, lane = tid & 63;
    int l31 = lane & 31, g = lane >> 5;
    int bi = blockIdx.x;
    int wh = bi & 1, h = (bi >> 1) & 255, b = bi >> 9;
    int w0 = wh * 128;
    int pxb = wave * 32;
    f32x16 acc = {};

    for (int ck = 0; ck < 4; ++ck) {
        if (!((cmask >> ck) & 1)) continue;
        int c0 = ck * 32;
        // stage 3x130x32 f16 (16B units, swizzled)
        for (int u = tid; u < 1560; u += 256) {
            int r = u / 520, rem = u - r * 520;
            int slot = rem >> 2, cg = rem & 3;
            int gh = h + r - 1, gw = w0 - 1 + slot;
            f16x8 v = {};
            if ((unsigned)gh < 256u && (unsigned)gw < 256u)
                v = *(const f16x8*)(feat + fidx(b, gh, gw) + c0 + cg * 8);
            *(f16x8*)(St + ((r * 130 + slot) * 4 + (cg ^ ((slot >> 1) & 3))) * 8) = v;
        }
        __syncthreads();
#pragma unroll
        for (int tap = 0; tap < 9; ++tap) {
            int ky = tap / 3, kx = tap - ky * 3;
            const f16* wp = Wt + (tap * 32 + l31) * 128 + c0 + g * 8;
            f16x8 a0 = *(const f16x8*)(wp);
            f16x8 a1 = *(const f16x8*)(wp + 16);
            int slot = pxb + l31 + kx;
            int rb = (ky * 130 + slot) * 4;
            int sw = (slot >> 1) & 3;
            f16x8 b0 = *(const f16x8*)(St + (rb + ((0 + g) ^ sw)) * 8);
            f16x8 b1 = *(const f16x8*)(St + (rb + ((2 + g) ^ sw)) * 8);
            acc = __builtin_amdgcn_mfma_f32_32x32x16_f16(a0, b0, acc, 0, 0, 0);
            acc = __builtin_amdgcn_mfma_f32_32x32x16_f16(a1, b1, acc, 0, 0, 0);
        }
        __syncthreads();
    }

    // epilogue: D col = lane&31 (px), row = (r&3)+8*(r>>2)+4*(lane>>5) (oc)
    int px = w0 + pxb + l31;
    f16* op = feat + fidx(b, h, px) + outbase;
#pragma unroll
    for (int r = 0; r < 16; r += 2) {
        int oc0 = (r & 3) + 8 * (r >> 2) + 4 * g;
        float b0v = bias[oc0];
        float b1v = (oc0 + 1 < COUT) ? bias[oc0 + 1] : 0.f;
        float v0 = acc[r] + b0v;
        float v1 = acc[r + 1] + b1v;
        v0 = (v0 >= 0.f) ? v0 : 0.2f * v0;
        v1 = (v1 >= 0.f) ? v1 : 0.2f * v1;
        if (oc0 + 1 < COUT) {
            f16x2 pr = {(f16)v0, (f16)v1};
            *(f16x2*)(op + oc0) = pr;
        } else if (oc0 < COUT) {
            op[oc0] = (f16)v0;
        }
    }
}

// Deterministic 2-stage pooling: partial sums per (sample, px-block).
__global__ __launch_bounds__(256) void pool_part_k(const f16* __restrict__ feat,
                                                   float* __restrict__ part) {
    __shared__ float red[4][128];
    int bi = blockIdx.x;
    int b = bi >> 5, pb = bi & 31;
    int t = threadIdx.x;
    int cp = t & 63, ps = t >> 6;
    int px0 = pb * 2048 + ps * 512;
    float s0 = 0.f, s1 = 0.f;
    const f16* base = feat + (size_t)b * HW * CH + (size_t)px0 * CH + cp * 2;
    for (int i = 0; i < 512; ++i) {
        f16x2 v = *(const f16x2*)(base + (size_t)i * CH);
        s0 += (float)v[0];
        s1 += (float)v[1];
    }
    red[ps][cp * 2] = s0;
    red[ps][cp * 2 + 1] = s1;
    __syncthreads();
    if (t < 128) {
        float s = red[0][t] + red[1][t] + red[2][t] + red[3][t];
        part[((size_t)b * 32 + pb) * 128 + t] = s;
    }
}

__global__ __launch_bounds__(256) void pool_fin_k(const float* __restrict__ part,
                                                  float* __restrict__ pooled) {
    int gid = blockIdx.x * 256 + threadIdx.x;
    if (gid >= 1024) return;
    int b = gid >> 7, pc = gid & 127;
    float s = 0.f;
    for (int pb = 0; pb < 32; ++pb) s += part[((size_t)b * 32 + pb) * 128 + pc];
    int lc = (pc == 127) ? 0 : pc + 1;
    pooled[b * 128 + lc] = s * (1.f / 65536.f);
}

__global__ __launch_bounds__(256) void mlp1_k(const float* __restrict__ pooled,
                                              const float* __restrict__ w1,
                                              const float* __restrict__ g,
                                              const float* __restrict__ bb,
                                              float* __restrict__ hbuf) {
    int t = threadIdx.x;
    int b = t >> 5, r = t & 31;
    float s = 0.f;
    for (int c = 0; c < 128; ++c) s += pooled[b * 128 + c] * w1[r * 128 + c];
    s = s * g[r] + bb[r];
    hbuf[t] = (s > 0.f) ? s : 0.f;
}

__global__ __launch_bounds__(256) void mlp2_k(const float* __restrict__ hbuf,
                                              const float* __restrict__ w2,
                                              const float* __restrict__ b2,
                                              float* __restrict__ wgen) {
    int idx = blockIdx.x * 256 + threadIdx.x;
    if (idx >= 8 * 6272) return;
    int b = idx / 6272, i = idx - b * 6272;
    float s = b2[i];
    for (int r = 0; r < 32; ++r) s += hbuf[b * 32 + r] * w2[i * 32 + r];
    wgen[idx] = s;
}

// Fused dynamic 7x7 depthwise (+bias,+lrelu) -> 3x3 conv (3 oc), NHWC f16,
// channel-chunked by 32. One block = 16x16 output tile.
__global__ __launch_bounds__(256) void dwc5_k(const f16* __restrict__ feat,
                                              const float* __restrict__ wgen,
                                              const float* __restrict__ dwb,
                                              const float* __restrict__ c5w,
                                              const float* __restrict__ c5b,
                                              float* __restrict__ out) {
    __shared__ f16 Ft[24 * 24 * 32];   // 36864 B
    __shared__ f16 Xt[18 * 18 * 32];   // 20736 B
    __shared__ f16 Wd[32 * 49];        // 3136 B  (dw weights, f16)
    __shared__ float Wb[32];           // 128 B
    __shared__ f16 W5[3 * 9 * 32];     // 1728 B   -> total 62592 B

    int tid = threadIdx.x;
    int bi = blockIdx.x;
    int b = bi >> 8, rem = bi & 255;
    int th0 = (rem >> 4) << 4, tw0 = (rem & 15) << 4;
    int ty = tid >> 4, tx = tid & 15;
    int cl = tid & 31, sid = tid >> 5;
    float acc[3] = {0.f, 0.f, 0.f};

    for (int ck = 0; ck < 4; ++ck) {
        int c0 = ck * 32;
        // stage 24x24x32 feat tile
        for (int u = tid; u < 2304; u += 256) {
            int p = u >> 2, cg = u & 3;
            int y = p / 24, xx = p - y * 24;
            int gh = th0 - 4 + y, gw = tw0 - 4 + xx;
            f16x8 v = {};
            if ((unsigned)gh < 256u && (unsigned)gw < 256u)
                v = *(const f16x8*)(feat + fidx(b, gh, gw) + c0 + cg * 8);
            *(f16x8*)(Ft + p * 32 + cg * 8) = v;
        }
        // stage dw weights/bias + conv5 weights for this chunk
        for (int i = tid; i < 32 * 49; i += 256) {
            int c = i / 49, tp = i - c * 49;
            int pc = c0 + c;
            int lc = (pc == 127) ? 0 : pc + 1;
            Wd[c * 49 + tp] = (f16)wgen[b * 6272 + lc * 49 + tp];
        }
        if (tid < 32) {
            int pc = c0 + tid;
            Wb[tid] = dwb[(pc == 127) ? 0 : pc + 1];
        }
        for (int i = tid; i < 3 * 9 * 32; i += 256) {
            int oc = i / 288, r2 = i - oc * 288;
            int tp = r2 >> 5, c = r2 & 31;
            int pc = c0 + c;
            int lc = (pc == 127) ? 0 : pc + 1;
            W5[i] = (f16)c5w[(oc * 128 + lc) * 9 + tp];
        }
        __syncthreads();

        // depthwise: thread owns one channel, pairs of adjacent px
        float w[49];
#pragma unroll
        for (int k = 0; k < 49; ++k) w[k] = (float)Wd[cl * 49 + k];
        float bc = Wb[cl];
        for (int pid = sid; pid < 162; pid += 8) {
            int y = pid / 9, x0 = (pid - y * 9) * 2;
            float a0 = 0.f, a1 = 0.f;
#pragma unroll
            for (int ky = 0; ky < 7; ++ky) {
                int rbase = ((y + ky) * 24 + x0) * 32 + cl;
                float f[8];
#pragma unroll
                for (int kx = 0; kx < 8; ++kx) f[kx] = (float)Ft[rbase + kx * 32];
#pragma unroll
                for (int kx = 0; kx < 7; ++kx) {
                    a0 = fmaf(f[kx], w[ky * 7 + kx], a0);
                    a1 = fmaf(f[kx + 1], w[ky * 7 + kx], a1);
                }
            }
            a0 += bc; a1 += bc;
            a0 = (a0 >= 0.f) ? a0 : 0.2f * a0;
            a1 = (a1 >= 0.f) ? a1 : 0.2f * a1;
            int gy = th0 - 1 + y, gx = tw0 - 1 + x0;
            if ((unsigned)gy >= 256u) { a0 = 0.f; a1 = 0.f; }
            if ((unsigned)gx >= 256u) a0 = 0.f;
            if ((unsigned)(gx + 1) >= 256u) a1 = 0.f;
            Xt[(y * 18 + x0) * 32 + cl] = (f16)a0;
            Xt[(y * 18 + x0 + 1) * 32 + cl] = (f16)a1;
        }
        __syncthreads();

        // conv5 partial accumulation over this chunk (thread = output px)
#pragma unroll
        for (int tap = 0; tap < 9; ++tap) {
            int ky = tap / 3, kx = tap - ky * 3;
            int xb = ((ty + ky) * 18 + (tx + kx)) * 32;
#pragma unroll
            for (int j = 0; j < 4; ++j) {
                f16x8 xv = *(const f16x8*)(Xt + xb + j * 8);
#pragma unroll
                for (int oc = 0; oc < 3; ++oc) {
                    f16x8 wv = *(const f16x8*)(W5 + (oc * 9 + tap) * 32 + j * 8);
#if __has_builtin(__builtin_amdgcn_fdot2)
#pragma unroll
                    for (int p2 = 0; p2 < 4; ++p2) {
                        f16x2 xp = {xv[2 * p2], xv[2 * p2 + 1]};
                        f16x2 wp = {wv[2 * p2], wv[2 * p2 + 1]};
                        acc[oc] = __builtin_amdgcn_fdot2(xp, wp, acc[oc], false);
                    }
#else
#pragma unroll
                    for (int e = 0; e < 8; ++e)
                        acc[oc] = fmaf((float)xv[e], (float)wv[e], acc[oc]);
#endif
                }
            }
        }
        __syncthreads();
    }

    size_t ob = ((size_t)b * 3) * HW + (size_t)(th0 + ty) * IMG + (tw0 + tx);
    out[ob] = acc[0] + c5b[0];
    out[ob + HW] = acc[1] + c5b[1];
    out[ob + 2 * HW] = acc[2] + c5b[2];
}

extern "C" void kernel_launch(void* const* d_in, const int* in_sizes, int n_in,
                              void* d_out, int out_size, void* d_ws, size_t ws_size,
                              hipStream_t stream) {
    (void)in_sizes; (void)n_in; (void)out_size; (void)ws_size;
    const float* x     = (const float*)d_in[0];
    const float* c1w   = (const float*)d_in[1];
    const float* c1b   = (const float*)d_in[2];
    const float* c2w   = (const float*)d_in[3];
    const float* c2b   = (const float*)d_in[4];
    const float* c3w   = (const float*)d_in[5];
    const float* c3b   = (const float*)d_in[6];
    const float* c4w   = (const float*)d_in[7];
    const float* c4b   = (const float*)d_in[8];
    const float* dw_w1 = (const float*)d_in[9];
    const float* bn_g  = (const float*)d_in[10];
    const float* bn_b  = (const float*)d_in[11];
    const float* dw_w2 = (const float*)d_in[12];
    const float* dw_b2 = (const float*)d_in[13];
    const float* dwb   = (const float*)d_in[14];
    const float* c5w   = (const float*)d_in[15];
    const float* c5b   = (const float*)d_in[16];
    float* out = (float*)d_out;

    f16* feat = (f16*)d_ws;                              // 8*65536*128 halfs
    f16* Wt   = feat + (size_t)8 * HW * CH;              // 3*36864 halfs
    f16* Wt2 = Wt, *Wt3 = Wt + 36864, *Wt4 = Wt + 73728;
    float* part   = (float*)(Wt + 3 * 36864);            // 8*32*128
    float* pooled = part + 8 * 32 * 128;                 // 1024
    float* hbuf   = pooled + 1024;                       // 256
    float* wgen   = hbuf + 256;                          // 50176

    prep_wt_k<<<144, 256, 0, stream>>>(c2w, Wt2, 33, 32);
    prep_wt_k<<<144, 256, 0, stream>>>(c3w, Wt3, 65, 32);
    prep_wt_k<<<144, 256, 0, stream>>>(c4w, Wt4, 97, 31);

    conv1_k<<<2048, 256, 0, stream>>>(x, feat, c1w, c1b);
    convm_k<<<4096, 256, 0, stream>>>(feat, Wt2, c2b, 32, 0b1001, 32);
    convm_k<<<4096, 256, 0, stream>>>(feat, Wt3, c3b, 64, 0b1011, 32);
    convm_k<<<4096, 256, 0, stream>>>(feat, Wt4, c4b, 96, 0b1111, 31);

    pool_part_k<<<256, 256, 0, stream>>>(feat, part);
    pool_fin_k<<<4, 256, 0, stream>>>(part, pooled);
    mlp1_k<<<1, 256, 0, stream>>>(pooled, dw_w1, bn_g, bn_b, hbuf);
    mlp2_k<<<196, 256, 0, stream>>>(hbuf, dw_w2, dw_b2, wgen);

    dwc5_k<<<2048, 256, 0, stream>>>(feat, wgen, dwb, c5w, c5b, out);
}